// Round 14
// baseline (113.530 us; speedup 1.0000x reference)
//
#include <hip/hip_runtime.h>
#include <hip/hip_bf16.h>
#include <float.h>

#define DI   64
#define DOUT 62
#define CI   3
#define CO   16
#define NB   16
constexpr int SP    = DOUT * DOUT * DOUT;    // 238328 (even)
constexpr int NPART = 256;                   // 16 h-tiles x 16 d-tiles
constexpr int XDW   = NB * CI * DI * DI * DI / 2;   // 6,291,456 bf16-pair dwords

typedef __attribute__((ext_vector_type(8))) short bf16x8;
typedef __attribute__((ext_vector_type(4))) float f32x4;

// Module BSS scratch (fully rewritten every call)
__device__ float g_psum[NB * CO * NPART];
__device__ float g_psq [NB * CO * NPART];
__device__ float g_stats[NB * CO * 2];
__device__ uint4 g_wb4[4 * 64];              // per-lane B fragments
__device__ unsigned int g_xbf[XDW];          // x as packed bf16 pairs (~25 MB)

__device__ __forceinline__ unsigned short f2bf(float v) {
    __hip_bfloat16 h = __float2bfloat16(v);
    return __builtin_bit_cast(unsigned short, h);
}
__device__ __forceinline__ unsigned int pk2(float lo, float hi) {
    return (unsigned int)f2bf(lo) | ((unsigned int)f2bf(hi) << 16);
}

// Pre-pass: x fp32 -> packed bf16 pairs (HBM-bound, ~12 us)
__global__ __launch_bounds__(256) void x2bf_kernel(const float* __restrict__ x)
{
    int i = blockIdx.x * 256 + threadIdx.x;
    const int stride = gridDim.x * 256;
    for (; i < XDW / 2; i += stride) {           // 4 floats per iter
        const float4 v = ((const float4*)x)[i];
        uint2 u;
        u.x = pk2(v.x, v.y);
        u.y = pk2(v.z, v.w);
        ((uint2*)g_xbf)[i] = u;
    }
}

// Pack B[k][o]: k = t*32 + (lane>>4)*8 + j ; tap k -> (g=k>>2, r=k&3),
// g -> (i,kd,kh). Zero for r==3 or g>=27 (K padding).
__global__ void reorg_w_kernel(const float* __restrict__ w)
{
    unsigned int* dst = (unsigned int*)g_wb4;
    for (int d = threadIdx.x; d < 4 * 64 * 4; d += 256) {
        const int t    = d >> 8;
        const int lane = (d >> 2) & 63;
        const int dw   = d & 3;
        const int o    = lane & 15, q = lane >> 4;
        unsigned int u = 0;
        for (int half = 0; half < 2; ++half) {
            const int j = dw * 2 + half;
            const int k = t * 32 + q * 8 + j;
            const int g = k >> 2, r = k & 3;
            float val = 0.f;
            if (g < 27 && r < 3) {
                const int i = g / 9, kd = (g % 9) / 3, kh = g % 3;
                val = w[o * 81 + i * 27 + kd * 9 + kh * 3 + r];
            }
            u |= ((unsigned int)f2bf(val)) << (16 * half);
        }
        dst[d] = u;
    }
}

// ---------------------------------------------------------------------------
// MFMA implicit-GEMM conv. Block (64,4): wave ty owns depth row d0+ty.
// Staging from pre-converted g_xbf: phase0 = raw dwords, phase1 via alignbit.
// RSTR=34 (bank shift 2/row; R12's 33 caused 6.9M conflict-cycles).
// MODE 0: stats only. 1: stats + y[n][ch][sp] bf16. 2: recompute -> out.
// ---------------------------------------------------------------------------
template <int MODE>
__global__ __launch_bounds__(256) void conv_mfma_kernel(
    const float* __restrict__ b, const float* __restrict__ m,
    unsigned int* __restrict__ y32, float* __restrict__ out)
{
    constexpr int RSTR = 34;                 // dword row stride
    constexpr int PH   = 3 * 36 * RSTR;      // 3672 dwords per phase
    __shared__ unsigned int xs[2 * PH];      // 29376 B
    __shared__ float redS[4][CO], redQ[4][CO];

    const int lane = threadIdx.x, ty = threadIdx.y;
    const int h0 = blockIdx.x * 4, d0 = blockIdx.y * 4, n = blockIdx.z;

    // ---- stage: copy bf16 rows; derive odd-w phase with alignbit ----
    const int tid = ty * 64 + lane;
    for (int idx = tid; idx < 108 * 32; idx += 256) {
        const int row = idx >> 5, t = idx & 31;
        const int i = row / 36, rm = row % 36, p = rm / 6, hr = rm % 6;
        const int dg = min(d0 + p, DI - 1), hg = min(h0 + hr, DI - 1);
        const unsigned int* src = g_xbf + ((((n * CI + i) * DI + dg) * DI) + hg) * 32;
        const unsigned int u0 = src[t];
        const unsigned int u1 = src[min(t + 1, 31)];     // t=31 hi-half is junk-safe
        xs[row * RSTR + t]      = u0;
        xs[PH + row * RSTR + t] = __builtin_amdgcn_alignbit(u1, u0, 16);
    }
    __syncthreads();

    const int c = lane & 15, q = lane >> 4;
    const int phase = c & 1, chalf = c >> 1;

    // Resident B fragments
    bf16x8 wf[4];
#pragma unroll
    for (int t = 0; t < 4; ++t)
        wf[t] = __builtin_bit_cast(bf16x8, g_wb4[t * 64 + lane]);

    // Per-lane tap-row offsets (dwords)
    int RB[4][2];
#pragma unroll
    for (int t = 0; t < 4; ++t)
#pragma unroll
        for (int s = 0; s < 2; ++s) {
            int g = t * 8 + q * 2 + s;
            if (g > 26) g = 26;                     // pad groups read junk*0
            const int i = g / 9, kd = (g % 9) / 3, kh = g % 3;
            RB[t][s] = (i * 36 + kd * 6 + kh) * RSTR;
        }

    const float bc = b[c], mc = m[c];
    const float bcm = bc * mc;
    float mu = 0.f, is = 1.f;
    if (MODE == 2) {
        mu = g_stats[(n * CO + c) * 2 + 0];
        is = g_stats[(n * CO + c) * 2 + 1];
    }

    const int d = d0 + ty;
    const bool dvalid = d < DOUT;
    float sSum = 0.f, qSum = 0.f;

    if (dvalid) {
#pragma unroll
        for (int hh = 0; hh < 4; ++hh) {
            const int h = h0 + hh;
            if (h < DOUT) {
                const int tb = (ty * 6 + hh) * RSTR + (phase ? PH : 0) + chalf;
#pragma unroll
                for (int wt = 0; wt < 4; ++wt) {
                    const int tb2 = tb + wt * 8;
                    f32x4 acc = {0.f, 0.f, 0.f, 0.f};
#pragma unroll
                    for (int t = 0; t < 4; ++t) {
                        const int i0 = tb2 + RB[t][0];
                        const int i1 = tb2 + RB[t][1];
                        uint4 av;
                        av.x = xs[i0]; av.y = xs[i0 + 1];
                        av.z = xs[i1]; av.w = xs[i1 + 1];
                        const bf16x8 af = __builtin_bit_cast(bf16x8, av);
                        acc = __builtin_amdgcn_mfma_f32_16x16x32_bf16(af, wf[t], acc, 0, 0, 0);
                    }
                    const int wbase = wt * 16 + q * 4;          // <= 60
                    const size_t spbase = ((size_t)(d * DOUT + h)) * DOUT + wbase;
                    if (MODE == 2) {
#pragma unroll
                        for (int r = 0; r < 4; ++r) {
                            float v = fmaf(acc[r], mc, bcm);
                            float z = (v - mu) * is;
                            z = fminf(fmaxf(z, -1.f), 1.f) * mc;
#pragma unroll
                            for (int off = 1; off < 16; off <<= 1)
                                z = fmaxf(z, __shfl_xor(z, off));
                            if (c == 0 && wbase + r < DOUT)
                                out[(size_t)n * SP + spbase + r] = z;
                        }
                    } else {
                        const float v0 = fmaf(acc[0], mc, bcm);
                        const float v1 = fmaf(acc[1], mc, bcm);
                        const float v2 = fmaf(acc[2], mc, bcm);
                        const float v3 = fmaf(acc[3], mc, bcm);
                        const bool full = (wbase < 60);          // wbase+3 < 62
                        sSum += v0 + v1;  qSum += v0 * v0 + v1 * v1;
                        if (full) { sSum += v2 + v3; qSum += v2 * v2 + v3 * v3; }
                        if (MODE == 1) {
                            unsigned int* yp =
                                y32 + (((size_t)(n * CO + c) * SP + spbase) >> 1);
                            yp[0] = pk2(v0, v1);
                            if (full) yp[1] = pk2(v2, v3);
                        }
                    }
                }
            }
        }
    }

    if (MODE != 2) {
        sSum += __shfl_xor(sSum, 16); qSum += __shfl_xor(qSum, 16);
        sSum += __shfl_xor(sSum, 32); qSum += __shfl_xor(qSum, 32);
        if (lane < 16) { redS[ty][c] = sSum; redQ[ty][c] = qSum; }
        __syncthreads();
        if (ty == 0 && lane < 16) {
            const float s  = redS[0][lane] + redS[1][lane] + redS[2][lane] + redS[3][lane];
            const float qq = redQ[0][lane] + redQ[1][lane] + redQ[2][lane] + redQ[3][lane];
            const int blk = blockIdx.y * 16 + blockIdx.x;       // 0..255
            g_psum[(n * CO + lane) * NPART + blk] = s;
            g_psq [(n * CO + lane) * NPART + blk] = qq;
        }
    }
}

// Reduce 256 partials per (n,c) -> mean, invstd
__global__ __launch_bounds__(256) void finalize_stats_kernel()
{
    const int idx = blockIdx.x;              // n*16 + o
    const int tid = threadIdx.x;
    __shared__ float ls[256], lq[256];
    ls[tid] = g_psum[idx * NPART + tid];
    lq[tid] = g_psq [idx * NPART + tid];
    __syncthreads();
    for (int off = 128; off > 0; off >>= 1) {
        if (tid < off) { ls[tid] += ls[tid + off]; lq[tid] += lq[tid + off]; }
        __syncthreads();
    }
    if (tid == 0) {
        const float inv_n = 1.0f / (float)SP;
        const float mean = ls[0] * inv_n;
        const float var  = fmaxf(lq[0] * inv_n - mean * mean, 0.f);
        g_stats[idx * 2 + 0] = mean;
        g_stats[idx * 2 + 1] = rsqrtf(var + 1e-5f);
    }
}

// Pass 2: y[n][ch][sp] bf16 pairs; per-channel coalesced dword reads; 2 sp/thread
__global__ __launch_bounds__(256) void pass2_kernel(
    const unsigned int* __restrict__ y32, const float* __restrict__ m,
    float* __restrict__ out)
{
    const int n = blockIdx.y;
    const int t = blockIdx.x * 256 + threadIdx.x;
    if (t >= SP / 2) return;
    const float* st = g_stats + n * CO * 2;
    const unsigned int* yn = y32 + ((size_t)n * CO * SP) / 2 + t;
    float mx0 = -FLT_MAX, mx1 = -FLT_MAX;
#pragma unroll
    for (int o = 0; o < CO; ++o) {
        const unsigned int u = yn[(size_t)o * (SP / 2)];
        const float a0 = __uint_as_float(u << 16);
        const float a1 = __uint_as_float(u & 0xFFFF0000u);
        const float mu = st[o * 2], is = st[o * 2 + 1], mo = m[o];
        const float z0 = fminf(fmaxf((a0 - mu) * is, -1.f), 1.f) * mo;
        const float z1 = fminf(fmaxf((a1 - mu) * is, -1.f), 1.f) * mo;
        mx0 = fmaxf(mx0, z0); mx1 = fmaxf(mx1, z1);
    }
    ((float2*)out)[(size_t)n * (SP / 2) + t] = make_float2(mx0, mx1);
}

extern "C" void kernel_launch(void* const* d_in, const int* in_sizes, int n_in,
                              void* d_out, int out_size, void* d_ws, size_t ws_size,
                              hipStream_t stream)
{
    const float* x = (const float*)d_in[0];
    const float* w = (const float*)d_in[1];
    const float* b = (const float*)d_in[2];
    const float* m = (const float*)d_in[3];
    float* out = (float*)d_out;

    const dim3 blk(64, 4);
    const dim3 grd(16, 16, NB);
    const size_t yBytes = (size_t)NB * SP * CO * 2;   // ~122 MB

    x2bf_kernel<<<dim3(2048), dim3(256), 0, stream>>>(x);
    reorg_w_kernel<<<dim3(1), dim3(256), 0, stream>>>(w);

    if (ws_size >= yBytes) {
        unsigned int* y = (unsigned int*)d_ws;
        conv_mfma_kernel<1><<<grd, blk, 0, stream>>>(b, m, y, nullptr);
        finalize_stats_kernel<<<dim3(NB * CO), dim3(256), 0, stream>>>();
        pass2_kernel<<<dim3((SP / 2 + 255) / 256, NB), dim3(256), 0, stream>>>(y, m, out);
    } else {
        conv_mfma_kernel<0><<<grd, blk, 0, stream>>>(b, m, nullptr, nullptr);
        finalize_stats_kernel<<<dim3(NB * CO), dim3(256), 0, stream>>>();
        conv_mfma_kernel<2><<<grd, blk, 0, stream>>>(b, m, nullptr, out);
    }
}

// Round 15
// 103.256 us; speedup vs baseline: 1.0995x; 1.0995x over previous
//
#include <hip/hip_runtime.h>
#include <hip/hip_bf16.h>
#include <float.h>

#define DI   64
#define DOUT 62
#define CI   3
#define CO   16
#define NB   16
constexpr int SP    = DOUT * DOUT * DOUT;    // 238328 (even)
constexpr int HT    = 31;                    // h-tiles of 2
constexpr int DT    = 16;                    // d-tiles of 4
constexpr int NPART = HT * DT;               // 496 partials per (n,c)
constexpr int XDW   = NB * CI * DI * DI * DI / 2;   // bf16-pair dwords

typedef __attribute__((ext_vector_type(8))) short bf16x8;
typedef __attribute__((ext_vector_type(4))) float f32x4;

// Module BSS scratch (fully rewritten every call)
__device__ float g_psum[NB * CO * NPART];
__device__ float g_psq [NB * CO * NPART];
__device__ float g_stats[NB * CO * 2];
__device__ uint4 g_wb4[4 * 64];              // per-lane B fragments
__device__ unsigned int g_xbf[XDW];          // x as packed bf16 pairs (~25 MB)

__device__ __forceinline__ unsigned short f2bf(float v) {
    __hip_bfloat16 h = __float2bfloat16(v);
    return __builtin_bit_cast(unsigned short, h);
}
__device__ __forceinline__ unsigned int pk2(float lo, float hi) {
    return (unsigned int)f2bf(lo) | ((unsigned int)f2bf(hi) << 16);
}

// Pre-pass: x fp32 -> packed bf16 pairs (HBM-bound, ~12 us)
__global__ __launch_bounds__(256) void x2bf_kernel(const float* __restrict__ x)
{
    int i = blockIdx.x * 256 + threadIdx.x;
    const int stride = gridDim.x * 256;
    for (; i < XDW / 2; i += stride) {
        const float4 v = ((const float4*)x)[i];
        uint2 u;
        u.x = pk2(v.x, v.y);
        u.y = pk2(v.z, v.w);
        ((uint2*)g_xbf)[i] = u;
    }
}

// K-mapping: MFMA t, lane-quarter q -> pair P = t*4+q -> groups (2P, 2P+1).
// k-slot j: j<4 -> (gA=2P, r=j); j>=4 -> (gB=2P+1, r=j-4). r==3 or g>26 -> 0.
__global__ void reorg_w_kernel(const float* __restrict__ w)
{
    unsigned int* dst = (unsigned int*)g_wb4;
    for (int dwi = threadIdx.x; dwi < 4 * 64 * 4; dwi += 256) {
        const int t    = dwi >> 8;
        const int lane = (dwi >> 2) & 63;
        const int dw   = dwi & 3;
        const int o    = lane & 15, q = lane >> 4;
        const int P    = t * 4 + q;
        unsigned int u = 0;
        for (int half = 0; half < 2; ++half) {
            const int j = dw * 2 + half;
            const int g = (j < 4) ? (2 * P) : (2 * P + 1);
            const int r = j & 3;
            float val = 0.f;
            if (g <= 26 && r < 3) {
                const int i = g / 9, kd = (g % 9) / 3, kh = g % 3;
                val = w[o * 81 + i * 27 + kd * 9 + kh * 3 + r];
            }
            u |= ((unsigned int)f2bf(val)) << (16 * half);
        }
        dst[dwi] = u;
    }
}

__device__ __forceinline__ int rowOf(int g, int dl, int hl) {
    const int i = g / 9, kd = (g % 9) / 3, kh = g % 3;
    return (i * 6 + (dl + kd)) * 4 + (hl + kh);   // slab row [(i*6+p)*4+hr]
}

// ---------------------------------------------------------------------------
// MFMA conv, aligned-b64 A-gather. Block (64,8): wave ty -> (dl=ty>>1, hl=ty&1)
// output row (d0+dl, h0+hl). Position map: w = 4*m + wt (m = D-row). 4-phase
// slab: phase p dword t = bf16 positions {2t+p, 2t+p+1}; lane m reads dwords
// (2m, 2m+1) -> ds_read_b64 aligned. 72 rows x 4 phases x RSTR=34 = 39 KB.
// MODE 0: stats only. 1: stats + y[n][ch][sp] bf16. 2: recompute -> out.
// ---------------------------------------------------------------------------
template <int MODE>
__global__ __launch_bounds__(512) void conv_mfma_kernel(
    const float* __restrict__ b, const float* __restrict__ m,
    unsigned int* __restrict__ y32, float* __restrict__ out)
{
    constexpr int RSTR = 34;
    constexpr int PH   = 72 * RSTR;          // 2448 dwords per phase
    __shared__ unsigned int xs[4 * PH];      // 39168 B
    __shared__ float redS[8][CO], redQ[8][CO];

    const int lane = threadIdx.x, ty = threadIdx.y;
    const int h0 = blockIdx.x * 2, d0 = blockIdx.y * 4, n = blockIdx.z;
    const int tid = ty * 64 + lane;

    // ---- stage 4 phase-interleavings of the 72-row slab ----
    for (int idx = tid; idx < 72 * 32; idx += 512) {
        const int row = idx >> 5, t = idx & 31;
        const int i = row / 24, rm = row % 24, p = rm >> 2, hr = rm & 3;
        const int dg = min(d0 + p, DI - 1);
        const int hg = h0 + hr;                            // <= 63 always
        const unsigned int* src = g_xbf + (((n * CI + i) * DI + dg) * DI + hg) * 32;
        const unsigned int u0 = src[t];
        const unsigned int u1 = src[min(t + 1, 31)];
        const unsigned int u2 = src[min(t + 2, 31)];
        xs[0 * PH + row * RSTR + t] = u0;
        xs[1 * PH + row * RSTR + t] = __builtin_amdgcn_alignbit(u1, u0, 16);
        xs[2 * PH + row * RSTR + t] = u1;
        xs[3 * PH + row * RSTR + t] = __builtin_amdgcn_alignbit(u2, u1, 16);
    }
    __syncthreads();

    const int c = lane & 15, q = lane >> 4;
    const int dl = ty >> 1, hl = ty & 1;

    // Resident B fragments
    bf16x8 wf[4];
#pragma unroll
    for (int t = 0; t < 4; ++t)
        wf[t] = __builtin_bit_cast(bf16x8, g_wb4[t * 64 + lane]);

    // Per-lane tap-row offsets (pre-scaled by RSTR); pads -> row 0 (junk*0)
    int RA[4], RB_[4];
#pragma unroll
    for (int t = 0; t < 4; ++t) {
        const int P = t * 4 + q;
        const int gA = 2 * P, gB = 2 * P + 1;
        RA[t]  = (gA <= 26) ? rowOf(gA, dl, hl) * RSTR : 0;
        RB_[t] = (gB <= 26) ? rowOf(gB, dl, hl) * RSTR : 0;
    }

    const float bc = b[c], mc = m[c];
    const float bcm = bc * mc;
    float mu = 0.f, is = 1.f;
    if (MODE == 2) {
        mu = g_stats[(n * CO + c) * 2 + 0];
        is = g_stats[(n * CO + c) * 2 + 1];
    }

    const int d = d0 + dl, h = h0 + hl;
    const bool dvalid = d < DOUT;
    float sS = 0.f, qS = 0.f;

    if (dvalid) {
        f32x4 acc[4];
#pragma unroll
        for (int wt = 0; wt < 4; ++wt) {
            const unsigned int* xp = xs + wt * PH + (c << 1);
            f32x4 a = {0.f, 0.f, 0.f, 0.f};
#pragma unroll
            for (int t = 0; t < 4; ++t) {
                const uint2 lo = *(const uint2*)(xp + RA[t]);   // ds_read_b64
                const uint2 hi = *(const uint2*)(xp + RB_[t]);  // ds_read_b64
                uint4 av;
                av.x = lo.x; av.y = lo.y; av.z = hi.x; av.w = hi.y;
                a = __builtin_amdgcn_mfma_f32_16x16x32_bf16(
                        __builtin_bit_cast(bf16x8, av), wf[t], a, 0, 0, 0);
            }
            acc[wt] = a;
        }

        // lane holds channel c, positions w = 16q + p, p = 4*reg + wt
        const size_t spb = (size_t)(d * DOUT + h) * DOUT + 16 * q;

        if (MODE == 2) {
#pragma unroll
            for (int reg = 0; reg < 4; ++reg)
#pragma unroll
                for (int wt = 0; wt < 4; ++wt) {
                    const int p = reg * 4 + wt;
                    const float val = fmaf(acc[wt][reg], mc, bcm);
                    float z = fminf(fmaxf((val - mu) * is, -1.f), 1.f) * mc;
                    z = fmaxf(z, __shfl_xor(z, 1));
                    z = fmaxf(z, __shfl_xor(z, 2));
                    z = fmaxf(z, __shfl_xor(z, 4));
                    z = fmaxf(z, __shfl_xor(z, 8));
                    if (c == p && (p < 14 || q < 3))
                        out[(size_t)n * SP + spb + p] = z;
                }
        } else {
            float v[16];
#pragma unroll
            for (int reg = 0; reg < 4; ++reg)
#pragma unroll
                for (int wt = 0; wt < 4; ++wt) {
                    const int p = reg * 4 + wt;
                    float val = fmaf(acc[wt][reg], mc, bcm);
                    if (p >= 14) val = (q < 3) ? val : 0.f;   // pos 62,63 invalid
                    v[p] = val;
                    sS += val; qS += val * val;
                }
            if (MODE == 1) {
                unsigned int* yp = y32 + (((size_t)(n * CO + c) * SP + spb) >> 1);
#pragma unroll
                for (int s = 0; s < 7; ++s)
                    yp[s] = pk2(v[2 * s], v[2 * s + 1]);
                if (q < 3) yp[7] = pk2(v[14], v[15]);
            }
        }
    }

    if (MODE != 2) {
        sS += __shfl_xor(sS, 16); qS += __shfl_xor(qS, 16);
        sS += __shfl_xor(sS, 32); qS += __shfl_xor(qS, 32);
        if (lane < 16) { redS[ty][c] = sS; redQ[ty][c] = qS; }
        __syncthreads();
        if (ty == 0 && lane < 16) {
            float s = 0.f, qq = 0.f;
#pragma unroll
            for (int wv = 0; wv < 8; ++wv) { s += redS[wv][lane]; qq += redQ[wv][lane]; }
            const int blk = blockIdx.y * HT + blockIdx.x;    // 0..495
            g_psum[(n * CO + lane) * NPART + blk] = s;
            g_psq [(n * CO + lane) * NPART + blk] = qq;
        }
    }
}

// Reduce 496 partials per (n,c) -> mean, invstd
__global__ __launch_bounds__(256) void finalize_stats_kernel()
{
    const int idx = blockIdx.x;              // n*16 + o
    const int tid = threadIdx.x;
    __shared__ float ls[256], lq[256];
    float s = g_psum[idx * NPART + tid];
    float q = g_psq [idx * NPART + tid];
    if (tid + 256 < NPART) {
        s += g_psum[idx * NPART + tid + 256];
        q += g_psq [idx * NPART + tid + 256];
    }
    ls[tid] = s; lq[tid] = q;
    __syncthreads();
    for (int off = 128; off > 0; off >>= 1) {
        if (tid < off) { ls[tid] += ls[tid + off]; lq[tid] += lq[tid + off]; }
        __syncthreads();
    }
    if (tid == 0) {
        const float inv_n = 1.0f / (float)SP;
        const float mean = ls[0] * inv_n;
        const float var  = fmaxf(lq[0] * inv_n - mean * mean, 0.f);
        g_stats[idx * 2 + 0] = mean;
        g_stats[idx * 2 + 1] = rsqrtf(var + 1e-5f);
    }
}

// Pass 2: y[n][ch][sp] bf16 pairs; per-channel coalesced dword reads; 2 sp/thread
__global__ __launch_bounds__(256) void pass2_kernel(
    const unsigned int* __restrict__ y32, const float* __restrict__ m,
    float* __restrict__ out)
{
    const int n = blockIdx.y;
    const int t = blockIdx.x * 256 + threadIdx.x;
    if (t >= SP / 2) return;
    const float* st = g_stats + n * CO * 2;
    const unsigned int* yn = y32 + ((size_t)n * CO * SP) / 2 + t;
    float mx0 = -FLT_MAX, mx1 = -FLT_MAX;
#pragma unroll
    for (int o = 0; o < CO; ++o) {
        const unsigned int u = yn[(size_t)o * (SP / 2)];
        const float a0 = __uint_as_float(u << 16);
        const float a1 = __uint_as_float(u & 0xFFFF0000u);
        const float mu = st[o * 2], is = st[o * 2 + 1], mo = m[o];
        const float z0 = fminf(fmaxf((a0 - mu) * is, -1.f), 1.f) * mo;
        const float z1 = fminf(fmaxf((a1 - mu) * is, -1.f), 1.f) * mo;
        mx0 = fmaxf(mx0, z0); mx1 = fmaxf(mx1, z1);
    }
    ((float2*)out)[(size_t)n * (SP / 2) + t] = make_float2(mx0, mx1);
}

extern "C" void kernel_launch(void* const* d_in, const int* in_sizes, int n_in,
                              void* d_out, int out_size, void* d_ws, size_t ws_size,
                              hipStream_t stream)
{
    const float* x = (const float*)d_in[0];
    const float* w = (const float*)d_in[1];
    const float* b = (const float*)d_in[2];
    const float* m = (const float*)d_in[3];
    float* out = (float*)d_out;

    const dim3 blk(64, 8);
    const dim3 grd(HT, DT, NB);
    const size_t yBytes = (size_t)NB * SP * CO * 2;   // ~122 MB

    x2bf_kernel<<<dim3(2048), dim3(256), 0, stream>>>(x);
    reorg_w_kernel<<<dim3(1), dim3(256), 0, stream>>>(w);

    if (ws_size >= yBytes) {
        unsigned int* y = (unsigned int*)d_ws;
        conv_mfma_kernel<1><<<grd, blk, 0, stream>>>(b, m, y, nullptr);
        finalize_stats_kernel<<<dim3(NB * CO), dim3(256), 0, stream>>>();
        pass2_kernel<<<dim3((SP / 2 + 255) / 256, NB), dim3(256), 0, stream>>>(y, m, out);
    } else {
        conv_mfma_kernel<0><<<grd, blk, 0, stream>>>(b, m, nullptr, nullptr);
        finalize_stats_kernel<<<dim3(NB * CO), dim3(256), 0, stream>>>();
        conv_mfma_kernel<2><<<grd, blk, 0, stream>>>(b, m, nullptr, out);
    }
}

// Round 16
// 93.598 us; speedup vs baseline: 1.2130x; 1.1032x over previous
//
#include <hip/hip_runtime.h>
#include <hip/hip_bf16.h>
#include <float.h>

#define DI   64
#define DOUT 62
#define CI   3
#define CO   16
#define NB   16
constexpr int SP    = DOUT * DOUT * DOUT;    // 238328
constexpr int SP64  = DOUT * DOUT * 64;      // padded per-channel y extent 246016
constexpr int HT    = 31;                    // h-tiles of 2
constexpr int DT    = 16;                    // d-tiles of 4
constexpr int NPART = HT * DT;               // 496
constexpr int XDW   = NB * CI * DI * DI * DI / 2;
constexpr int RSTR  = 34;                    // slab dword row stride
constexpr int PHD   = 72 * RSTR;             // 2448 dwords per phase

typedef __attribute__((ext_vector_type(8))) short bf16x8;
typedef __attribute__((ext_vector_type(4))) float f32x4;

// Module BSS scratch (fully rewritten every call)
__device__ float g_psum[NB * CO * NPART];
__device__ float g_psq [NB * CO * NPART];
__device__ float g_stats[NB * CO * 2];       // (A, B') per (n,c): z = a*A + B'
__device__ uint4 g_wb4[4 * 64];              // per-lane B fragments
__device__ uint2 g_rt [4 * 64];              // per-lane row offsets (x RSTR) for gA,gB
__device__ unsigned int g_xbf[XDW];          // x as packed bf16 pairs (~25 MB)

__device__ __forceinline__ unsigned short f2bf(float v) {
    __hip_bfloat16 h = __float2bfloat16(v);
    return __builtin_bit_cast(unsigned short, h);
}
__device__ __forceinline__ unsigned int pk2(float lo, float hi) {
    return (unsigned int)f2bf(lo) | ((unsigned int)f2bf(hi) << 16);
}

// Pre-pass: x fp32 -> packed bf16 pairs (HBM-bound, ~12 us)
__global__ __launch_bounds__(256) void x2bf_kernel(const float* __restrict__ x)
{
    int i = blockIdx.x * 256 + threadIdx.x;
    const int stride = gridDim.x * 256;
    for (; i < XDW / 2; i += stride) {
        const float4 v = ((const float4*)x)[i];
        uint2 u;
        u.x = pk2(v.x, v.y);
        u.y = pk2(v.z, v.w);
        ((uint2*)g_xbf)[i] = u;
    }
}

// K-mapping: MFMA t, lane-quarter q -> pair P = t*4+q -> groups (2P, 2P+1).
// Also build per-lane slab-row-offset table: baseRow(g) = i*24+kd*4+kh (x RSTR).
__global__ void reorg_w_kernel(const float* __restrict__ w)
{
    unsigned int* dst = (unsigned int*)g_wb4;
    for (int dwi = threadIdx.x; dwi < 4 * 64 * 4; dwi += 256) {
        const int t    = dwi >> 8;
        const int lane = (dwi >> 2) & 63;
        const int dw   = dwi & 3;
        const int o    = lane & 15, q = lane >> 4;
        const int P    = t * 4 + q;
        unsigned int u = 0;
        for (int half = 0; half < 2; ++half) {
            const int j = dw * 2 + half;
            const int g = (j < 4) ? (2 * P) : (2 * P + 1);
            const int r = j & 3;
            float val = 0.f;
            if (g <= 26 && r < 3) {
                const int i = g / 9, kd = (g % 9) / 3, kh = g % 3;
                val = w[o * 81 + i * 27 + kd * 9 + kh * 3 + r];
            }
            u |= ((unsigned int)f2bf(val)) << (16 * half);
        }
        dst[dwi] = u;
    }
    if (threadIdx.x < 256) {
        const int t = threadIdx.x >> 6, lane = threadIdx.x & 63;
        const int q = lane >> 4, P = t * 4 + q;
        uint2 rt;
        const int gA = 2 * P, gB = 2 * P + 1;
        rt.x = (gA <= 26) ? ((gA / 9) * 24 + ((gA % 9) / 3) * 4 + gA % 3) * RSTR : 0;
        rt.y = (gB <= 26) ? ((gB / 9) * 24 + ((gB % 9) / 3) * 4 + gB % 3) * RSTR : 0;
        g_rt[t * 64 + lane] = rt;
    }
}

// ---------------------------------------------------------------------------
// MFMA conv. Block (64,8): wave ty -> (dl=ty>>1, hl=ty&1). Position w = 4m+wt.
// 4-phase slab (w-shifts 0..3), aligned ds_read_b64 A-gather; staging via one
// uint2 load + shfl neighbors + alignbit + 4x ds_write_b64 per 2 dword slots.
// Bias/m deferred: stats & y carry RAW acc; finalize folds (A,B').
// MODE 0: stats only. 1: stats + y[n][ch][d][h][64] bf16. 2: recompute -> out.
// ---------------------------------------------------------------------------
template <int MODE>
__global__ __launch_bounds__(512) void conv_mfma_kernel(
    const float* __restrict__ m,
    unsigned int* __restrict__ y32, float* __restrict__ out)
{
    __shared__ unsigned int xs[4 * PHD];     // 39168 B
    __shared__ float redS[8][CO], redQ[8][CO];

    const int lane = threadIdx.x, ty = threadIdx.y;
    const int h0 = blockIdx.x * 2, d0 = blockIdx.y * 4, n = blockIdx.z;
    const int tid = ty * 64 + lane;

    // ---- stage 4 phase-interleavings (2 dword slots per iteration) ----
    for (int idx = tid; idx < 72 * 16; idx += 512) {
        const int row = idx >> 4, t = (idx & 15) * 2;
        const int i = row / 24, rm = row % 24, p = rm >> 2, hr = rm & 3;
        const int dg = min(d0 + p, DI - 1);
        const uint2 u = *(const uint2*)(g_xbf +
                          (((n * CI + i) * DI + dg) * DI + (h0 + hr)) * 32 + t);
        const unsigned D2 = __shfl_down(u.x, 1);   // next slot's lo (junk at tails: masked outputs only)
        const unsigned D3 = __shfl_down(u.y, 1);
        const unsigned a10 = __builtin_amdgcn_alignbit(u.y, u.x, 16);
        const unsigned a21 = __builtin_amdgcn_alignbit(D2, u.y, 16);
        const unsigned a32 = __builtin_amdgcn_alignbit(D3, D2, 16);
        unsigned int* dp = xs + row * RSTR + t;
        *(uint2*)(dp + 0 * PHD) = u;
        *(uint2*)(dp + 1 * PHD) = make_uint2(a10, a21);
        *(uint2*)(dp + 2 * PHD) = make_uint2(u.y, D2);
        *(uint2*)(dp + 3 * PHD) = make_uint2(a21, a32);
    }
    __syncthreads();

    const int c = lane & 15, q = lane >> 4;
    const int dl = ty >> 1, hl = ty & 1;
    const int offr = ((dl << 2) + hl) * RSTR;

    // Resident B fragments + A-gather addresses (dword units)
    bf16x8 wf[4];
    int aA[4], aB[4];
#pragma unroll
    for (int t = 0; t < 4; ++t) {
        wf[t] = __builtin_bit_cast(bf16x8, g_wb4[t * 64 + lane]);
        const uint2 rt = g_rt[t * 64 + lane];
        aA[t] = (int)rt.x + offr + 2 * c;
        aB[t] = (int)rt.y + offr + 2 * c;
    }

    const float mc = m[c];
    float A = 0.f, Bp = 0.f;
    if (MODE == 2) {
        A  = g_stats[(n * CO + c) * 2 + 0];
        Bp = g_stats[(n * CO + c) * 2 + 1];
    }

    const int d = d0 + dl, h = h0 + hl;
    const bool dvalid = d < DOUT;
    float sS = 0.f, qS = 0.f;

    if (dvalid) {
        f32x4 acc[4];
#pragma unroll
        for (int wt = 0; wt < 4; ++wt) {
            f32x4 a = {0.f, 0.f, 0.f, 0.f};
#pragma unroll
            for (int t = 0; t < 4; ++t) {
                const uint2 lo = *(const uint2*)(xs + wt * PHD + aA[t]);
                const uint2 hi = *(const uint2*)(xs + wt * PHD + aB[t]);
                uint4 av;
                av.x = lo.x; av.y = lo.y; av.z = hi.x; av.w = hi.y;
                a = __builtin_amdgcn_mfma_f32_16x16x32_bf16(
                        __builtin_bit_cast(bf16x8, av), wf[t], a, 0, 0, 0);
            }
            acc[wt] = a;
        }

        if (MODE == 2) {
            const size_t spb = (size_t)(d * DOUT + h) * DOUT + 16 * q;
#pragma unroll
            for (int reg = 0; reg < 4; ++reg)
#pragma unroll
                for (int wt = 0; wt < 4; ++wt) {
                    const int p = reg * 4 + wt;
                    float z = fminf(fmaxf(fmaf(acc[wt][reg], A, Bp), -1.f), 1.f) * mc;
                    z = fmaxf(z, __shfl_xor(z, 1));
                    z = fmaxf(z, __shfl_xor(z, 2));
                    z = fmaxf(z, __shfl_xor(z, 4));
                    z = fmaxf(z, __shfl_xor(z, 8));
                    if (c == p && (p < 14 || q < 3))
                        out[(size_t)n * SP + spb + p] = z;
                }
        } else {
            // stats on raw acc (invalid positions w=62,63 zeroed: q==3, reg==3, wt>=2)
#pragma unroll
            for (int wt = 0; wt < 4; ++wt)
#pragma unroll
                for (int reg = 0; reg < 4; ++reg) {
                    float a = acc[wt][reg];
                    if ((wt >= 2) && (reg == 3)) a = (q < 3) ? a : 0.f;
                    sS += a; qS = fmaf(a, a, qS);
                }
            if (MODE == 1) {
                const size_t ypd = (size_t)(n * CO + c) * (SP64 / 2)
                                 + (size_t)(d * DOUT + h) * 32 + 8 * q;  // dword idx, 16B-aligned
                uint4 s0, s1;
                s0.x = pk2(acc[0][0], acc[1][0]); s0.y = pk2(acc[2][0], acc[3][0]);
                s0.z = pk2(acc[0][1], acc[1][1]); s0.w = pk2(acc[2][1], acc[3][1]);
                s1.x = pk2(acc[0][2], acc[1][2]); s1.y = pk2(acc[2][2], acc[3][2]);
                s1.z = pk2(acc[0][3], acc[1][3]); s1.w = pk2(acc[2][3], acc[3][3]);
                *(uint4*)(y32 + ypd)     = s0;
                *(uint4*)(y32 + ypd + 4) = s1;    // w=62,63 land in the pad, skipped by pass2
            }
        }
    }

    if (MODE != 2) {
        sS += __shfl_xor(sS, 16); qS += __shfl_xor(qS, 16);
        sS += __shfl_xor(sS, 32); qS += __shfl_xor(qS, 32);
        if (lane < 16) { redS[ty][c] = sS; redQ[ty][c] = qS; }
        __syncthreads();
        if (ty == 0 && lane < 16) {
            float s = 0.f, qq = 0.f;
#pragma unroll
            for (int wv = 0; wv < 8; ++wv) { s += redS[wv][lane]; qq += redQ[wv][lane]; }
            const int blk = blockIdx.y * HT + blockIdx.x;    // 0..495
            g_psum[(n * CO + lane) * NPART + blk] = s;
            g_psq [(n * CO + lane) * NPART + blk] = qq;
        }
    }
}

// Reduce 496 partials per (n,c) -> (A, B'):  z = a*A + B'
// v=(a+b)*m: var_v = m^2 var_a; z=(v-mu_v)*rsqrt(var_v+eps) = m*(a-mu_a)*is -> b drops out.
__global__ __launch_bounds__(256) void finalize_stats_kernel(const float* __restrict__ m)
{
    const int idx = blockIdx.x;              // n*16 + o
    const int tid = threadIdx.x;
    __shared__ float ls[256], lq[256];
    float s = g_psum[idx * NPART + tid];
    float q = g_psq [idx * NPART + tid];
    if (tid + 256 < NPART) {
        s += g_psum[idx * NPART + tid + 256];
        q += g_psq [idx * NPART + tid + 256];
    }
    ls[tid] = s; lq[tid] = q;
    __syncthreads();
    for (int off = 128; off > 0; off >>= 1) {
        if (tid < off) { ls[tid] += ls[tid + off]; lq[tid] += lq[tid + off]; }
        __syncthreads();
    }
    if (tid == 0) {
        const float inv_n = 1.0f / (float)SP;
        const float muA = ls[0] * inv_n;
        const float varA = fmaxf(lq[0] * inv_n - muA * muA, 0.f);
        const float mo = m[idx & 15];
        const float isv = rsqrtf(fmaf(mo * mo, varA, 1e-5f));
        const float A = mo * isv;
        g_stats[idx * 2 + 0] = A;
        g_stats[idx * 2 + 1] = -muA * A;
    }
}

// Pass 2: y[n][ch][d][h][64] raw-acc bf16; z = a*A+B', clamp, *m, channel-max
__global__ __launch_bounds__(256) void pass2_kernel(
    const unsigned int* __restrict__ y32, const float* __restrict__ m,
    float* __restrict__ out)
{
    const int n = blockIdx.y;
    const int t = blockIdx.x * 256 + threadIdx.x;
    if (t >= DOUT * DOUT * 32) return;
    const int wp = t & 31;
    if (wp == 31) return;                    // pad dword (w=62,63)
    const int row = t >> 5;                  // d*62 + h
    const float* st = g_stats + n * CO * 2;
    const unsigned int* yn = y32 + (size_t)n * CO * (SP64 / 2) + t;
    float mx0 = -FLT_MAX, mx1 = -FLT_MAX;
#pragma unroll
    for (int o = 0; o < CO; ++o) {
        const unsigned int u = yn[(size_t)o * (SP64 / 2)];
        const float a0 = __uint_as_float(u << 16);
        const float a1 = __uint_as_float(u & 0xFFFF0000u);
        const float A = st[o * 2], Bp = st[o * 2 + 1], mo = m[o];
        const float z0 = fminf(fmaxf(fmaf(a0, A, Bp), -1.f), 1.f) * mo;
        const float z1 = fminf(fmaxf(fmaf(a1, A, Bp), -1.f), 1.f) * mo;
        mx0 = fmaxf(mx0, z0); mx1 = fmaxf(mx1, z1);
    }
    const int sp = row * DOUT + 2 * wp;
    *(float2*)(out + (size_t)n * SP + sp) = make_float2(mx0, mx1);
}

extern "C" void kernel_launch(void* const* d_in, const int* in_sizes, int n_in,
                              void* d_out, int out_size, void* d_ws, size_t ws_size,
                              hipStream_t stream)
{
    const float* x = (const float*)d_in[0];
    const float* w = (const float*)d_in[1];
    const float* m = (const float*)d_in[3];
    float* out = (float*)d_out;

    const dim3 blk(64, 8);
    const dim3 grd(HT, DT, NB);
    const size_t yBytes = (size_t)NB * CO * SP64 * 2;   // ~126 MB (w padded to 64)

    x2bf_kernel<<<dim3(2048), dim3(256), 0, stream>>>(x);
    reorg_w_kernel<<<dim3(1), dim3(256), 0, stream>>>(w);

    if (ws_size >= yBytes) {
        unsigned int* y = (unsigned int*)d_ws;
        conv_mfma_kernel<1><<<grd, blk, 0, stream>>>(m, y, nullptr);
        finalize_stats_kernel<<<dim3(NB * CO), dim3(256), 0, stream>>>(m);
        pass2_kernel<<<dim3((DOUT * DOUT * 32 + 255) / 256, NB), dim3(256), 0, stream>>>(y, m, out);
    } else {
        conv_mfma_kernel<0><<<grd, blk, 0, stream>>>(m, nullptr, nullptr);
        finalize_stats_kernel<<<dim3(NB * CO), dim3(256), 0, stream>>>(m);
        conv_mfma_kernel<2><<<grd, blk, 0, stream>>>(m, nullptr, out);
    }
}